// Round 5
// baseline (273.075 us; speedup 1.0000x reference)
//
#include <hip/hip_runtime.h>

#define M_VERT 32768
#define NBATCH 8
#define FIN 32
#define RANK 5
#define FILT 32
#define E_NNZ 262144
#define EPAD (E_NNZ + 7 * M_VERT)     // upper bound on 8-padded edge count
#define SLICE ((size_t)M_VERT * FIN)  // elements per n-slice of a T buffer

typedef short short8 __attribute__((ext_vector_type(8)));
typedef float f32x4 __attribute__((ext_vector_type(4)));

__device__ __forceinline__ float bfl(unsigned int u) {           // low bf16 -> f32
    unsigned int x = u << 16; return __builtin_bit_cast(float, x);
}
__device__ __forceinline__ float bfh(unsigned int u) {           // high bf16 -> f32
    unsigned int x = u & 0xffff0000u; return __builtin_bit_cast(float, x);
}
__device__ __forceinline__ unsigned int f2bf(float f) {          // f32 -> bf16 (RNE)
    unsigned int x = __builtin_bit_cast(unsigned int, f);
    return (x + 0x7fffu + ((x >> 16) & 1u)) >> 16;
}
__device__ __forceinline__ unsigned int pk(float a, float b) {
    return f2bf(a) | (f2bf(b) << 16);
}

// ---------------- CSR build (rows padded to multiples of 8) ----------------

__global__ void hist_kernel(const int* __restrict__ rows, int* __restrict__ cnt) {
    int e = blockIdx.x * blockDim.x + threadIdx.x;
    if (e < E_NNZ) atomicAdd(&cnt[rows[e]], 1);
}

// exclusive prefix sum of ceil8(cnt) -> rp[0..M]; re-zeroes fill cursor
__global__ __launch_bounds__(1024) void scan_kernel(const int* __restrict__ cnt,
                                                    int* __restrict__ rp,
                                                    int* __restrict__ fill) {
    __shared__ int sums[1024];
    int t = threadIdx.x;
    int base = t * 32;
    int local[32];
    int s = 0;
#pragma unroll
    for (int i = 0; i < 32; ++i) {
        int c = (cnt[base + i] + 7) & ~7;        // pad to multiple of 8
        local[i] = c; s += c;
    }
    sums[t] = s;
    __syncthreads();
    for (int off = 1; off < 1024; off <<= 1) {
        int add = (t >= off) ? sums[t - off] : 0;
        __syncthreads();
        sums[t] += add;
        __syncthreads();
    }
    int pre = (t == 0) ? 0 : sums[t - 1];
#pragma unroll
    for (int i = 0; i < 32; ++i) { rp[base + i] = pre; pre += local[i]; }
    if (t == 1023) rp[M_VERT] = pre;
#pragma unroll
    for (int i = 0; i < 32; ++i) fill[base + i] = 0;
}

__global__ void scatter_kernel(const int* __restrict__ rows, const int* __restrict__ cols,
                               const float* __restrict__ vals, const int* __restrict__ rp,
                               int* __restrict__ fill, int2* __restrict__ ev) {
    int e = blockIdx.x * blockDim.x + threadIdx.x;
    if (e < E_NNZ) {
        int r = rows[e];
        int pos = rp[r] + atomicAdd(&fill[r], 1);
        int2 p; p.x = cols[e]; p.y = __builtin_bit_cast(int, vals[e]);
        ev[pos] = p;
    }
}

// ---------------- pack x [N,M,Fin] fp32 -> T0 [N,M,Fin] bf16 (streaming) ----------------

__global__ void pack_kernel(const float* __restrict__ x, unsigned short* __restrict__ T0) {
    size_t tid = (size_t)blockIdx.x * blockDim.x + threadIdx.x;   // 8 elems each
    const float* src = x + tid * 8;
    float4 v0 = *(const float4*)(src);
    float4 v1 = *(const float4*)(src + 4);
    uint4 u;
    u.x = pk(v0.x, v0.y); u.y = pk(v0.z, v0.w);
    u.z = pk(v1.x, v1.y); u.w = pk(v1.z, v1.w);
    *(uint4*)(T0 + tid * 8) = u;
}

// ---------------- pack W fp32 -> MFMA B-fragment layout, bf16 ----------------
// Wb[((k*2+ft)*64 + lane)*8 + j] = bf16(W[(fin*5+k)*32 + ft*16 + (lane&15)]),
// fin = (lane>>4)*8 + j

__global__ void packw_kernel(const float* __restrict__ W, unsigned short* __restrict__ Wb) {
    int idx = blockIdx.x * blockDim.x + threadIdx.x;   // 640 total
    if (idx >= 640) return;
    int lane = idx & 63;
    int kf = idx >> 6;
    int k = kf >> 1, ft = kf & 1;
    int f = ft * 16 + (lane & 15);
    int fin0 = (lane >> 4) * 8;
    unsigned short tmp[8];
#pragma unroll
    for (int j = 0; j < 8; ++j)
        tmp[j] = (unsigned short)f2bf(W[((fin0 + j) * RANK + k) * FILT + f]);
    uint4 u;
    u.x = (unsigned int)tmp[0] | ((unsigned int)tmp[1] << 16);
    u.y = (unsigned int)tmp[2] | ((unsigned int)tmp[3] << 16);
    u.z = (unsigned int)tmp[4] | ((unsigned int)tmp[5] << 16);
    u.w = (unsigned int)tmp[6] | ((unsigned int)tmp[7] << 16);
    *(uint4*)(Wb + (size_t)idx * 8) = u;
}

// ---------------- SpMM phase (n-sliced): Tout = L*Tin  or  2*L*Tin - Tsub ----------------
// T layout [n][M][FIN]: per-n slice = 2 MiB -> L2-resident gathers.
// 8 lanes per row x 8B; 32 rows per block; grid n-major (blocks of one n
// dispatch together so the active gather working set stays ~1 slice).

__global__ __launch_bounds__(256) void spmmn_kernel(const int* __restrict__ rp,
                                                    const int2* __restrict__ ev,
                                                    const unsigned short* __restrict__ Tin,
                                                    const unsigned short* __restrict__ Tsub,
                                                    unsigned short* __restrict__ Tout, int cheb) {
    int t = threadIdx.x;
    int g = t >> 3;                       // row group 0..31
    int p = t & 7;                        // 8B slice of the 64B row
    int n  = blockIdx.x >> 10;            // 1024 row-blocks per n
    int rb = blockIdx.x & 1023;
    int m = rb * 32 + g;
    const unsigned short* Tn = Tin + (size_t)n * SLICE;
    int s = rp[m], e = rp[m + 1];
    float a0 = 0.f, a1 = 0.f, a2 = 0.f, a3 = 0.f;
    for (int j = s; j < e; j += 8) {
        uint4 e0 = *(const uint4*)(ev + j);       // {c0,v0,c1,v1}
        uint4 e1 = *(const uint4*)(ev + j + 2);
        uint4 e2 = *(const uint4*)(ev + j + 4);
        uint4 e3 = *(const uint4*)(ev + j + 6);
        uint2 t0 = *(const uint2*)(Tn + (size_t)e0.x * FIN + p * 4);
        uint2 t1 = *(const uint2*)(Tn + (size_t)e0.z * FIN + p * 4);
        uint2 t2 = *(const uint2*)(Tn + (size_t)e1.x * FIN + p * 4);
        uint2 t3 = *(const uint2*)(Tn + (size_t)e1.z * FIN + p * 4);
        uint2 t4 = *(const uint2*)(Tn + (size_t)e2.x * FIN + p * 4);
        uint2 t5 = *(const uint2*)(Tn + (size_t)e2.z * FIN + p * 4);
        uint2 t6 = *(const uint2*)(Tn + (size_t)e3.x * FIN + p * 4);
        uint2 t7 = *(const uint2*)(Tn + (size_t)e3.z * FIN + p * 4);
        float v;
        v = __builtin_bit_cast(float, e0.y);
        a0 += v * bfl(t0.x); a1 += v * bfh(t0.x); a2 += v * bfl(t0.y); a3 += v * bfh(t0.y);
        v = __builtin_bit_cast(float, e0.w);
        a0 += v * bfl(t1.x); a1 += v * bfh(t1.x); a2 += v * bfl(t1.y); a3 += v * bfh(t1.y);
        v = __builtin_bit_cast(float, e1.y);
        a0 += v * bfl(t2.x); a1 += v * bfh(t2.x); a2 += v * bfl(t2.y); a3 += v * bfh(t2.y);
        v = __builtin_bit_cast(float, e1.w);
        a0 += v * bfl(t3.x); a1 += v * bfh(t3.x); a2 += v * bfl(t3.y); a3 += v * bfh(t3.y);
        v = __builtin_bit_cast(float, e2.y);
        a0 += v * bfl(t4.x); a1 += v * bfh(t4.x); a2 += v * bfl(t4.y); a3 += v * bfh(t4.y);
        v = __builtin_bit_cast(float, e2.w);
        a0 += v * bfl(t5.x); a1 += v * bfh(t5.x); a2 += v * bfl(t5.y); a3 += v * bfh(t5.y);
        v = __builtin_bit_cast(float, e3.y);
        a0 += v * bfl(t6.x); a1 += v * bfh(t6.x); a2 += v * bfl(t6.y); a3 += v * bfh(t6.y);
        v = __builtin_bit_cast(float, e3.w);
        a0 += v * bfl(t7.x); a1 += v * bfh(t7.x); a2 += v * bfl(t7.y); a3 += v * bfh(t7.y);
    }
    size_t off = (size_t)n * SLICE + (size_t)m * FIN + p * 4;
    if (cheb) {
        uint2 o = *(const uint2*)(Tsub + off);
        a0 = 2.f * a0 - bfl(o.x); a1 = 2.f * a1 - bfh(o.x);
        a2 = 2.f * a2 - bfl(o.y); a3 = 2.f * a3 - bfh(o.y);
    }
    uint2 r;
    r.x = pk(a0, a1); r.y = pk(a2, a3);
    *(uint2*)(Tout + off) = r;
}

// ---------------- final GEMM: out[n,m,f] = bias[f] + sum_k T_k[n,m,:] @ W_k ----------------
// MFMA 16x16x32 bf16; T layout [n][M][FIN] -> A frag is one contiguous 16B load.
// 4 batches (n) per block; B frags in registers, reused across all 40 MFMAs.

__global__ __launch_bounds__(256, 4) void gemm_kernel(const unsigned short* __restrict__ T0,
                                                      const unsigned short* __restrict__ T1,
                                                      const unsigned short* __restrict__ T2,
                                                      const unsigned short* __restrict__ T3,
                                                      const unsigned short* __restrict__ T4,
                                                      const unsigned short* __restrict__ Wb,
                                                      const float* __restrict__ bias,
                                                      float* __restrict__ out) {
    int w = threadIdx.x >> 6;
    int l = threadIdx.x & 63;
    int g  = blockIdx.x & 1;          // n-group: n = g*4 + nn
    int mb = blockIdx.x >> 1;
    int m0 = (mb * 4 + w) * 16;
    int lrow = l & 15;                // A's m-offset AND C's column f
    int quad = l >> 4;

    short8 bfrag[5][2];
#pragma unroll
    for (int kf = 0; kf < 10; ++kf)
        bfrag[kf >> 1][kf & 1] = *(const short8*)(Wb + ((size_t)kf * 64 + l) * 8);

    float b0 = bias[lrow];
    float b1 = bias[16 + lrow];

    const unsigned short* Ts[5] = {T0, T1, T2, T3, T4};
    size_t rowoff = (size_t)(m0 + lrow) * FIN + quad * 8;

    f32x4 c0[4], c1[4];
#pragma unroll
    for (int nn = 0; nn < 4; ++nn) { c0[nn] = (f32x4){0.f,0.f,0.f,0.f}; c1[nn] = (f32x4){0.f,0.f,0.f,0.f}; }

#pragma unroll
    for (int k = 0; k < 5; ++k) {
        const unsigned short* p = Ts[k] + rowoff + (size_t)g * 4 * SLICE;
        short8 a0 = *(const short8*)(p);
        short8 a1 = *(const short8*)(p + SLICE);
        short8 a2 = *(const short8*)(p + 2 * SLICE);
        short8 a3 = *(const short8*)(p + 3 * SLICE);
        c0[0] = __builtin_amdgcn_mfma_f32_16x16x32_bf16(a0, bfrag[k][0], c0[0], 0, 0, 0);
        c1[0] = __builtin_amdgcn_mfma_f32_16x16x32_bf16(a0, bfrag[k][1], c1[0], 0, 0, 0);
        c0[1] = __builtin_amdgcn_mfma_f32_16x16x32_bf16(a1, bfrag[k][0], c0[1], 0, 0, 0);
        c1[1] = __builtin_amdgcn_mfma_f32_16x16x32_bf16(a1, bfrag[k][1], c1[1], 0, 0, 0);
        c0[2] = __builtin_amdgcn_mfma_f32_16x16x32_bf16(a2, bfrag[k][0], c0[2], 0, 0, 0);
        c1[2] = __builtin_amdgcn_mfma_f32_16x16x32_bf16(a2, bfrag[k][1], c1[2], 0, 0, 0);
        c0[3] = __builtin_amdgcn_mfma_f32_16x16x32_bf16(a3, bfrag[k][0], c0[3], 0, 0, 0);
        c1[3] = __builtin_amdgcn_mfma_f32_16x16x32_bf16(a3, bfrag[k][1], c1[3], 0, 0, 0);
    }

#pragma unroll
    for (int nn = 0; nn < 4; ++nn) {
        int n = g * 4 + nn;
        float* op = out + ((size_t)n * M_VERT + m0) * FILT;
#pragma unroll
        for (int r = 0; r < 4; ++r) {
            int orow = quad * 4 + r;
            op[(size_t)orow * FILT + lrow]      = c0[nn][r] + b0;
            op[(size_t)orow * FILT + 16 + lrow] = c1[nn][r] + b1;
        }
    }
}

// ---------------- launch ----------------

extern "C" void kernel_launch(void* const* d_in, const int* in_sizes, int n_in,
                              void* d_out, int out_size, void* d_ws, size_t ws_size,
                              hipStream_t stream) {
    const float* x    = (const float*)d_in[0];
    const float* vals = (const float*)d_in[1];
    const float* W    = (const float*)d_in[2];
    const float* bias = (const float*)d_in[3];
    const int*   rows = (const int*)d_in[4];
    const int*   cols = (const int*)d_in[5];
    float* out = (float*)d_out;

    // workspace: 5 bf16 T buffers (16 MiB each, layout [n][M][FIN]) + CSR + Wb
    const size_t TSZ = (size_t)NBATCH * SLICE;
    unsigned short* T0 = (unsigned short*)d_ws;
    unsigned short* T1 = T0 + TSZ;
    unsigned short* T2 = T1 + TSZ;
    unsigned short* T3 = T2 + TSZ;
    unsigned short* T4 = T3 + TSZ;
    int*  rp   = (int*)(T4 + TSZ);
    int*  fill = rp + (M_VERT + 2);
    int2* ev   = (int2*)(((uintptr_t)(fill + M_VERT) + 15) & ~(uintptr_t)15);  // 16B-aligned
    unsigned short* Wb = (unsigned short*)(ev + EPAD);

    hipMemsetAsync(fill, 0, M_VERT * sizeof(int), stream);
    hipMemsetAsync(ev, 0, (size_t)EPAD * sizeof(int2), stream);   // pad edges: col 0, val 0.0
    hist_kernel<<<E_NNZ / 256, 256, 0, stream>>>(rows, fill);
    scan_kernel<<<1, 1024, 0, stream>>>(fill, rp, fill);
    scatter_kernel<<<E_NNZ / 256, 256, 0, stream>>>(rows, cols, vals, rp, fill, ev);
    packw_kernel<<<3, 256, 0, stream>>>(W, Wb);
    pack_kernel<<<(NBATCH * M_VERT * FIN / 8) / 256, 256, 0, stream>>>(x, T0);

    // Chebyshev recurrence: 4 phase dispatches, each n-sliced for L2 residency
    spmmn_kernel<<<NBATCH * 1024, 256, 0, stream>>>(rp, ev, T0, T0, T1, 0);
    spmmn_kernel<<<NBATCH * 1024, 256, 0, stream>>>(rp, ev, T1, T0, T2, 1);
    spmmn_kernel<<<NBATCH * 1024, 256, 0, stream>>>(rp, ev, T2, T1, T3, 1);
    spmmn_kernel<<<NBATCH * 1024, 256, 0, stream>>>(rp, ev, T3, T2, T4, 1);

    // single fused epilogue GEMM
    gemm_kernel<<<(M_VERT / 64) * 2, 256, 0, stream>>>(T0, T1, T2, T3, T4, Wb, bias, out);
}

// Round 6
// 271.079 us; speedup vs baseline: 1.0074x; 1.0074x over previous
//
#include <hip/hip_runtime.h>

#define M_VERT 32768
#define NBATCH 8
#define FIN 32
#define RANK 5
#define FILT 32
#define E_NNZ 262144
#define EPAD (E_NNZ + 7 * M_VERT)     // upper bound on 8-padded edge count
#define SLICE ((size_t)M_VERT * FIN)  // elements per n-slice of a T buffer

typedef short short8 __attribute__((ext_vector_type(8)));
typedef float f32x4 __attribute__((ext_vector_type(4)));

__device__ __forceinline__ float bfl(unsigned int u) {           // low bf16 -> f32
    unsigned int x = u << 16; return __builtin_bit_cast(float, x);
}
__device__ __forceinline__ float bfh(unsigned int u) {           // high bf16 -> f32
    unsigned int x = u & 0xffff0000u; return __builtin_bit_cast(float, x);
}
__device__ __forceinline__ unsigned int f2bf(float f) {          // f32 -> bf16 (RNE)
    unsigned int x = __builtin_bit_cast(unsigned int, f);
    return (x + 0x7fffu + ((x >> 16) & 1u)) >> 16;
}
__device__ __forceinline__ unsigned int pk(float a, float b) {
    return f2bf(a) | (f2bf(b) << 16);
}

// ---------------- CSR build (rows padded to multiples of 8) ----------------

__global__ void hist_kernel(const int* __restrict__ rows, int* __restrict__ cnt) {
    int e = blockIdx.x * blockDim.x + threadIdx.x;
    if (e < E_NNZ) atomicAdd(&cnt[rows[e]], 1);
}

// exclusive prefix sum of ceil8(cnt) -> rp[0..M]; re-zeroes fill cursor
__global__ __launch_bounds__(1024) void scan_kernel(const int* __restrict__ cnt,
                                                    int* __restrict__ rp,
                                                    int* __restrict__ fill) {
    __shared__ int sums[1024];
    int t = threadIdx.x;
    int base = t * 32;
    int local[32];
    int s = 0;
#pragma unroll
    for (int i = 0; i < 32; ++i) {
        int c = (cnt[base + i] + 7) & ~7;        // pad to multiple of 8
        local[i] = c; s += c;
    }
    sums[t] = s;
    __syncthreads();
    for (int off = 1; off < 1024; off <<= 1) {
        int add = (t >= off) ? sums[t - off] : 0;
        __syncthreads();
        sums[t] += add;
        __syncthreads();
    }
    int pre = (t == 0) ? 0 : sums[t - 1];
#pragma unroll
    for (int i = 0; i < 32; ++i) { rp[base + i] = pre; pre += local[i]; }
    if (t == 1023) rp[M_VERT] = pre;
#pragma unroll
    for (int i = 0; i < 32; ++i) fill[base + i] = 0;
}

__global__ void scatter_kernel(const int* __restrict__ rows, const int* __restrict__ cols,
                               const float* __restrict__ vals, const int* __restrict__ rp,
                               int* __restrict__ fill, int2* __restrict__ ev) {
    int e = blockIdx.x * blockDim.x + threadIdx.x;
    if (e < E_NNZ) {
        int r = rows[e];
        int pos = rp[r] + atomicAdd(&fill[r], 1);
        int2 p; p.x = cols[e]; p.y = __builtin_bit_cast(int, vals[e]);
        ev[pos] = p;
    }
}

// ---------------- pack x [N,M,Fin] fp32 -> T0 [N,M,Fin] bf16 (streaming) ----------------

__global__ void pack_kernel(const float* __restrict__ x, unsigned short* __restrict__ T0) {
    size_t tid = (size_t)blockIdx.x * blockDim.x + threadIdx.x;   // 8 elems each
    const float* src = x + tid * 8;
    float4 v0 = *(const float4*)(src);
    float4 v1 = *(const float4*)(src + 4);
    uint4 u;
    u.x = pk(v0.x, v0.y); u.y = pk(v0.z, v0.w);
    u.z = pk(v1.x, v1.y); u.w = pk(v1.z, v1.w);
    *(uint4*)(T0 + tid * 8) = u;
}

// ---------------- pack W fp32 -> MFMA B-fragment layout, bf16 ----------------
// Wb[((k*2+ft)*64 + lane)*8 + j] = bf16(W[(fin*5+k)*32 + ft*16 + (lane&15)]),
// fin = (lane>>4)*8 + j

__global__ void packw_kernel(const float* __restrict__ W, unsigned short* __restrict__ Wb) {
    int idx = blockIdx.x * blockDim.x + threadIdx.x;   // 640 total
    if (idx >= 640) return;
    int lane = idx & 63;
    int kf = idx >> 6;
    int k = kf >> 1, ft = kf & 1;
    int f = ft * 16 + (lane & 15);
    int fin0 = (lane >> 4) * 8;
    unsigned short tmp[8];
#pragma unroll
    for (int j = 0; j < 8; ++j)
        tmp[j] = (unsigned short)f2bf(W[((fin0 + j) * RANK + k) * FILT + f]);
    uint4 u;
    u.x = (unsigned int)tmp[0] | ((unsigned int)tmp[1] << 16);
    u.y = (unsigned int)tmp[2] | ((unsigned int)tmp[3] << 16);
    u.z = (unsigned int)tmp[4] | ((unsigned int)tmp[5] << 16);
    u.w = (unsigned int)tmp[6] | ((unsigned int)tmp[7] << 16);
    *(uint4*)(Wb + (size_t)idx * 8) = u;
}

// ---------------- SpMM phase (n-sliced, XCD-pinned): Tout = L*Tin  or  2*L*Tin - Tsub ----
// T layout [n][M][FIN]: per-n slice = 2 MiB. n = blockIdx & 7 so that, under the
// round-robin blockIdx->XCD mapping, ALL blocks of slice n run on XCD n and the
// slice stays resident in that XCD's private 4 MiB L2 (gathers hit L2, not LLC).
// 8 lanes per row x 8B; 32 rows per block.

__global__ __launch_bounds__(256) void spmmn_kernel(const int* __restrict__ rp,
                                                    const int2* __restrict__ ev,
                                                    const unsigned short* __restrict__ Tin,
                                                    const unsigned short* __restrict__ Tsub,
                                                    unsigned short* __restrict__ Tout, int cheb) {
    int t = threadIdx.x;
    int g = t >> 3;                       // row group 0..31
    int p = t & 7;                        // 8B slice of the 64B row
    int n  = blockIdx.x & 7;              // XCD-pinned slice id (round-robin mapping)
    int rb = blockIdx.x >> 3;             // 1024 row-blocks per n
    int m = rb * 32 + g;
    const unsigned short* Tn = Tin + (size_t)n * SLICE;
    int s = rp[m], e = rp[m + 1];
    float a0 = 0.f, a1 = 0.f, a2 = 0.f, a3 = 0.f;
    for (int j = s; j < e; j += 8) {
        uint4 e0 = *(const uint4*)(ev + j);       // {c0,v0,c1,v1}
        uint4 e1 = *(const uint4*)(ev + j + 2);
        uint4 e2 = *(const uint4*)(ev + j + 4);
        uint4 e3 = *(const uint4*)(ev + j + 6);
        uint2 t0 = *(const uint2*)(Tn + (size_t)e0.x * FIN + p * 4);
        uint2 t1 = *(const uint2*)(Tn + (size_t)e0.z * FIN + p * 4);
        uint2 t2 = *(const uint2*)(Tn + (size_t)e1.x * FIN + p * 4);
        uint2 t3 = *(const uint2*)(Tn + (size_t)e1.z * FIN + p * 4);
        uint2 t4 = *(const uint2*)(Tn + (size_t)e2.x * FIN + p * 4);
        uint2 t5 = *(const uint2*)(Tn + (size_t)e2.z * FIN + p * 4);
        uint2 t6 = *(const uint2*)(Tn + (size_t)e3.x * FIN + p * 4);
        uint2 t7 = *(const uint2*)(Tn + (size_t)e3.z * FIN + p * 4);
        float v;
        v = __builtin_bit_cast(float, e0.y);
        a0 += v * bfl(t0.x); a1 += v * bfh(t0.x); a2 += v * bfl(t0.y); a3 += v * bfh(t0.y);
        v = __builtin_bit_cast(float, e0.w);
        a0 += v * bfl(t1.x); a1 += v * bfh(t1.x); a2 += v * bfl(t1.y); a3 += v * bfh(t1.y);
        v = __builtin_bit_cast(float, e1.y);
        a0 += v * bfl(t2.x); a1 += v * bfh(t2.x); a2 += v * bfl(t2.y); a3 += v * bfh(t2.y);
        v = __builtin_bit_cast(float, e1.w);
        a0 += v * bfl(t3.x); a1 += v * bfh(t3.x); a2 += v * bfl(t3.y); a3 += v * bfh(t3.y);
        v = __builtin_bit_cast(float, e2.y);
        a0 += v * bfl(t4.x); a1 += v * bfh(t4.x); a2 += v * bfl(t4.y); a3 += v * bfh(t4.y);
        v = __builtin_bit_cast(float, e2.w);
        a0 += v * bfl(t5.x); a1 += v * bfh(t5.x); a2 += v * bfl(t5.y); a3 += v * bfh(t5.y);
        v = __builtin_bit_cast(float, e3.y);
        a0 += v * bfl(t6.x); a1 += v * bfh(t6.x); a2 += v * bfl(t6.y); a3 += v * bfh(t6.y);
        v = __builtin_bit_cast(float, e3.w);
        a0 += v * bfl(t7.x); a1 += v * bfh(t7.x); a2 += v * bfl(t7.y); a3 += v * bfh(t7.y);
    }
    size_t off = (size_t)n * SLICE + (size_t)m * FIN + p * 4;
    if (cheb) {
        uint2 o = *(const uint2*)(Tsub + off);
        a0 = 2.f * a0 - bfl(o.x); a1 = 2.f * a1 - bfh(o.x);
        a2 = 2.f * a2 - bfl(o.y); a3 = 2.f * a3 - bfh(o.y);
    }
    uint2 r;
    r.x = pk(a0, a1); r.y = pk(a2, a3);
    *(uint2*)(Tout + off) = r;
}

// ---------------- final GEMM: out[n,m,f] = bias[f] + sum_k T_k[n,m,:] @ W_k ----------------
// MFMA 16x16x32 bf16; T layout [n][M][FIN] -> A frag is one contiguous 16B load.
// 4 batches (n) per block; B frags in registers, reused across all 40 MFMAs.

__global__ __launch_bounds__(256, 4) void gemm_kernel(const unsigned short* __restrict__ T0,
                                                      const unsigned short* __restrict__ T1,
                                                      const unsigned short* __restrict__ T2,
                                                      const unsigned short* __restrict__ T3,
                                                      const unsigned short* __restrict__ T4,
                                                      const unsigned short* __restrict__ Wb,
                                                      const float* __restrict__ bias,
                                                      float* __restrict__ out) {
    int w = threadIdx.x >> 6;
    int l = threadIdx.x & 63;
    int g  = blockIdx.x & 1;          // n-group: n = g*4 + nn
    int mb = blockIdx.x >> 1;
    int m0 = (mb * 4 + w) * 16;
    int lrow = l & 15;                // A's m-offset AND C's column f
    int quad = l >> 4;

    short8 bfrag[5][2];
#pragma unroll
    for (int kf = 0; kf < 10; ++kf)
        bfrag[kf >> 1][kf & 1] = *(const short8*)(Wb + ((size_t)kf * 64 + l) * 8);

    float b0 = bias[lrow];
    float b1 = bias[16 + lrow];

    const unsigned short* Ts[5] = {T0, T1, T2, T3, T4};
    size_t rowoff = (size_t)(m0 + lrow) * FIN + quad * 8;

    f32x4 c0[4], c1[4];
#pragma unroll
    for (int nn = 0; nn < 4; ++nn) { c0[nn] = (f32x4){0.f,0.f,0.f,0.f}; c1[nn] = (f32x4){0.f,0.f,0.f,0.f}; }

#pragma unroll
    for (int k = 0; k < 5; ++k) {
        const unsigned short* p = Ts[k] + rowoff + (size_t)g * 4 * SLICE;
        short8 a0 = *(const short8*)(p);
        short8 a1 = *(const short8*)(p + SLICE);
        short8 a2 = *(const short8*)(p + 2 * SLICE);
        short8 a3 = *(const short8*)(p + 3 * SLICE);
        c0[0] = __builtin_amdgcn_mfma_f32_16x16x32_bf16(a0, bfrag[k][0], c0[0], 0, 0, 0);
        c1[0] = __builtin_amdgcn_mfma_f32_16x16x32_bf16(a0, bfrag[k][1], c1[0], 0, 0, 0);
        c0[1] = __builtin_amdgcn_mfma_f32_16x16x32_bf16(a1, bfrag[k][0], c0[1], 0, 0, 0);
        c1[1] = __builtin_amdgcn_mfma_f32_16x16x32_bf16(a1, bfrag[k][1], c1[1], 0, 0, 0);
        c0[2] = __builtin_amdgcn_mfma_f32_16x16x32_bf16(a2, bfrag[k][0], c0[2], 0, 0, 0);
        c1[2] = __builtin_amdgcn_mfma_f32_16x16x32_bf16(a2, bfrag[k][1], c1[2], 0, 0, 0);
        c0[3] = __builtin_amdgcn_mfma_f32_16x16x32_bf16(a3, bfrag[k][0], c0[3], 0, 0, 0);
        c1[3] = __builtin_amdgcn_mfma_f32_16x16x32_bf16(a3, bfrag[k][1], c1[3], 0, 0, 0);
    }

#pragma unroll
    for (int nn = 0; nn < 4; ++nn) {
        int n = g * 4 + nn;
        float* op = out + ((size_t)n * M_VERT + m0) * FILT;
#pragma unroll
        for (int r = 0; r < 4; ++r) {
            int orow = quad * 4 + r;
            op[(size_t)orow * FILT + lrow]      = c0[nn][r] + b0;
            op[(size_t)orow * FILT + 16 + lrow] = c1[nn][r] + b1;
        }
    }
}

// ---------------- launch ----------------

extern "C" void kernel_launch(void* const* d_in, const int* in_sizes, int n_in,
                              void* d_out, int out_size, void* d_ws, size_t ws_size,
                              hipStream_t stream) {
    const float* x    = (const float*)d_in[0];
    const float* vals = (const float*)d_in[1];
    const float* W    = (const float*)d_in[2];
    const float* bias = (const float*)d_in[3];
    const int*   rows = (const int*)d_in[4];
    const int*   cols = (const int*)d_in[5];
    float* out = (float*)d_out;

    // workspace: 5 bf16 T buffers (16 MiB each, layout [n][M][FIN]) + CSR + Wb
    const size_t TSZ = (size_t)NBATCH * SLICE;
    unsigned short* T0 = (unsigned short*)d_ws;
    unsigned short* T1 = T0 + TSZ;
    unsigned short* T2 = T1 + TSZ;
    unsigned short* T3 = T2 + TSZ;
    unsigned short* T4 = T3 + TSZ;
    int*  rp   = (int*)(T4 + TSZ);
    int*  fill = rp + (M_VERT + 2);
    int2* ev   = (int2*)(((uintptr_t)(fill + M_VERT) + 15) & ~(uintptr_t)15);  // 16B-aligned
    unsigned short* Wb = (unsigned short*)(ev + EPAD);

    hipMemsetAsync(fill, 0, M_VERT * sizeof(int), stream);
    hipMemsetAsync(ev, 0, (size_t)EPAD * sizeof(int2), stream);   // pad edges: col 0, val 0.0
    hist_kernel<<<E_NNZ / 256, 256, 0, stream>>>(rows, fill);
    scan_kernel<<<1, 1024, 0, stream>>>(fill, rp, fill);
    scatter_kernel<<<E_NNZ / 256, 256, 0, stream>>>(rows, cols, vals, rp, fill, ev);
    packw_kernel<<<3, 256, 0, stream>>>(W, Wb);
    pack_kernel<<<(NBATCH * M_VERT * FIN / 8) / 256, 256, 0, stream>>>(x, T0);

    // Chebyshev recurrence: 4 phase dispatches, n-sliced + XCD-pinned (n = blk & 7)
    spmmn_kernel<<<NBATCH * 1024, 256, 0, stream>>>(rp, ev, T0, T0, T1, 0);
    spmmn_kernel<<<NBATCH * 1024, 256, 0, stream>>>(rp, ev, T1, T0, T2, 1);
    spmmn_kernel<<<NBATCH * 1024, 256, 0, stream>>>(rp, ev, T2, T1, T3, 1);
    spmmn_kernel<<<NBATCH * 1024, 256, 0, stream>>>(rp, ev, T3, T2, T4, 1);

    // single fused epilogue GEMM
    gemm_kernel<<<(M_VERT / 64) * 2, 256, 0, stream>>>(T0, T1, T2, T3, T4, Wb, bias, out);
}